// Round 13
// baseline (1052.105 us; speedup 1.0000x reference)
//
#include <hip/hip_runtime.h>
#include <hip/hip_bf16.h>
#include <stdint.h>

// Problem constants
#define BATCH 2
#define CIN 128
#define COUT 512
#define DD 8
#define PSPAT 8192          // D*H*W
#define NA 9                // anchors per position
#define NANCH 73728         // PSPAT*NA
#define PRE 2048
#define POST 300
#define CAP 4096            // candidate buffer (top-2048 + cutoff-bin ties)
#define NMS_TH 0.7f

// ws layout (byte offsets). Selection scratch aliases the Wt region, which is
// DEAD ONLY AFTER k_conv: hist is zeroed after k_conv (R10: zeroing it inside
// k_wtrans raced with Wt writes -> corrupted weights).
constexpr size_t OFF_WT   = 0;          // 27*128*512 f32   = 7,077,888 B
constexpr size_t OFF_WHT  = 7077888;    // 512*80 f32       = 163,840 B
constexpr size_t OFF_X    = 7241728;    // 2*512*8192 f32   = 33,554,432 B
constexpr size_t OFF_SC   = 40796160;   // 2*73728 f32      = 589,824 B
constexpr size_t OFF_BX   = 41385984;   // 2*73728*6 f32    = 3,538,944 B
constexpr size_t OFF_SB   = 44957696;   // 2*2048*6 f32     = 98,304 B
constexpr size_t OFF_MK   = 45056000;   // 2*2048*32 u64    = 1,048,576 B  (end 46,104,576)
// selection scratch inside [0, OFF_WT+7MB), used only after k_conv:
constexpr size_t OFF_HIST = 16;              // 2*65536 u32 = 524,288 B
constexpr size_t OFF_CAND = 524304;          // 2*4096 u64  = 65,536 B

// ---------------- fused weight transforms (one launch) ----------------
// Wht[c][q], q = og*10 + k (k<9 real), output o = og*9 + k  (8 groups of 9)
#define NT_WT   (27 * 128 * 512)
#define NT_WHT  (512 * 80)
__global__ void k_wtrans(const float* __restrict__ Wc, float* __restrict__ Wt,
                         const float* __restrict__ Wcls, const float* __restrict__ Wbb,
                         float* __restrict__ Wht) {
    int e = blockIdx.x * blockDim.x + threadIdx.x;
    if (e < NT_WT) {
        int co  = e & 511;
        int ci  = (e >> 9) & 127;
        int tap = e >> 16;
        Wt[e] = Wc[(co * 128 + ci) * 27 + tap];
        return;
    }
    e -= NT_WT;
    if (e >= NT_WHT) return;
    int q = e % 80;
    int c = e / 80;
    int og = q / 10, k = q % 10;
    int o = og * 9 + k;
    float v = 0.f;
    if (k < 9) v = (o < 18) ? Wcls[o * 512 + c] : Wbb[(o - 18) * 512 + c];
    Wht[e] = v;
}

// ---------------- conv3d 3x3x3 + bias + relu (implicit GEMM, fp32) ----------------
// FROZEN (R11/R12): at the LDS-throughput roofline for 8x8 frag / 256 thr /
// 128x128 tile (VALU 60-62% vs 67% analytic LDS cap). Named-float4 register
// prefetch (arrays always went to scratch/LDS; named vars are the only
// guaranteed-VGPR form). Stage order tap(asc valid range)->ci(0..127).

#define LDA4(J, V)                                                              \
    V.x = ok_ ? inb_[(size_t)(4 * (J) + 0) * 16384] : 0.f;                      \
    V.y = ok_ ? inb_[(size_t)(4 * (J) + 1) * 16384] : 0.f;                      \
    V.z = ok_ ? inb_[(size_t)(4 * (J) + 2) * 16384] : 0.f;                      \
    V.w = ok_ ? inb_[(size_t)(4 * (J) + 3) * 16384] : 0.f;

#define LDB4(J, V) V = *(const float4*)&wr_[(size_t)(kkB0 + 8 * (J)) * 512 + c4];

#define CONV_LD(S) do {                                                         \
    const int tap_ = tapBase + ((S) >> 1);                                      \
    const int cc_  = ((S) & 1) << 6;                                            \
    const int kd_ = tap_ / 9, kh_ = (tap_ / 3) % 3, kw_ = tap_ % 3;             \
    const int id_ = d0 + kd_ - 1;                                               \
    const int h_  = h0 + (spc >> 5) + kh_ - 1;                                  \
    const int w_  = (spc & 31) + kw_ - 1;                                       \
    const bool ok_ = ((unsigned)h_ < 32u) && ((unsigned)w_ < 32u);              \
    const float* inb_ = in + (((size_t)((b * CIN + cc_ + kkA0) * DD + id_)) << 10) \
                           + (h_ << 5) + w_;                                    \
    const float* wr_ = Wt + (size_t)(tap_ * 128 + cc_) * 512 + co0;             \
    LDA4(0, pa0) LDA4(1, pa1) LDA4(2, pa2) LDA4(3, pa3)                         \
    LDA4(4, pa4) LDA4(5, pa5) LDA4(6, pa6) LDA4(7, pa7)                         \
    LDB4(0, pw0) LDB4(1, pw1) LDB4(2, pw2) LDB4(3, pw3)                         \
    LDB4(4, pw4) LDB4(5, pw5) LDB4(6, pw6) LDB4(7, pw7)                         \
} while (0)

#define STA4(J, V)                                                              \
    As[(kkA0 + 2 * (4 * (J) + 0)) * 128 + spc] = V.x;                           \
    As[(kkA0 + 2 * (4 * (J) + 1)) * 128 + spc] = V.y;                           \
    As[(kkA0 + 2 * (4 * (J) + 2)) * 128 + spc] = V.z;                           \
    As[(kkA0 + 2 * (4 * (J) + 3)) * 128 + spc] = V.w;

#define STB4(J, V) *(float4*)&Bs[(kkB0 + 8 * (J)) * 128 + c4] = V;

#define CONV_ST do {                                                            \
    STA4(0, pa0) STA4(1, pa1) STA4(2, pa2) STA4(3, pa3)                         \
    STA4(4, pa4) STA4(5, pa5) STA4(6, pa6) STA4(7, pa7)                         \
    STB4(0, pw0) STB4(1, pw1) STB4(2, pw2) STB4(3, pw3)                         \
    STB4(4, pw4) STB4(5, pw5) STB4(6, pw6) STB4(7, pw7)                         \
} while (0)

__global__ __launch_bounds__(256, 2) void k_conv(const float* __restrict__ in,
                                                 const float* __restrict__ Wt,
                                                 const float* __restrict__ bconv,
                                                 float* __restrict__ x) {
    __shared__ __align__(16) float As[64 * 128];   // 32 KB
    __shared__ __align__(16) float Bs[64 * 128];   // 32 KB
    const int tid  = threadIdx.x;
    const int p0   = blockIdx.x * 128;   // spatial tile: fixed d, 4 h-rows
    const int co0  = blockIdx.y * 128;
    const int b    = blockIdx.z;
    const int d0   = p0 >> 10;
    const int h0   = (p0 >> 5) & 31;
    const int tp4  = (tid & 15) * 4;     // spatial frag base
    const int tco4 = (tid >> 4) * 4;     // cout frag base

    const int tapBase = (d0 == 0) ? 9 : 0;
    const int nTap    = 27 - (((d0 == 0) || (d0 == 7)) ? 9 : 0);
    const int NST     = nTap * 2;        // stages = taps x 2 ci-chunks of 64

    const int spc  = tid & 127;          // A: sp column
    const int kkA0 = tid >> 7;           // A: kk = kkA0 + 2i
    const int kkB0 = tid >> 5;           // B: kk = kkB0 + 8j
    const int c4   = (tid & 31) * 4;     // B: co within row

    float acc[8][8] = {};
    float4 pa0, pa1, pa2, pa3, pa4, pa5, pa6, pa7;   // A prefetch (32 floats)
    float4 pw0, pw1, pw2, pw3, pw4, pw5, pw6, pw7;   // B prefetch (8 float4)

    CONV_LD(0);
    CONV_ST;
    __syncthreads();

    for (int s = 0; s < NST; ++s) {
        const bool more = (s + 1 < NST);
        if (more) CONV_LD(s + 1);        // loads in flight during compute
        #pragma unroll 2
        for (int kk = 0; kk < 64; ++kk) {
            float4 a0 = *(const float4*)&As[kk * 128 + tp4];
            float4 a1 = *(const float4*)&As[kk * 128 + tp4 + 64];
            float4 b0 = *(const float4*)&Bs[kk * 128 + tco4];
            float4 b1 = *(const float4*)&Bs[kk * 128 + tco4 + 64];
            float av[8] = {a0.x, a0.y, a0.z, a0.w, a1.x, a1.y, a1.z, a1.w};
            float bv[8] = {b0.x, b0.y, b0.z, b0.w, b1.x, b1.y, b1.z, b1.w};
            #pragma unroll
            for (int i = 0; i < 8; ++i)
                #pragma unroll
                for (int j = 0; j < 8; ++j)
                    acc[i][j] += bv[i] * av[j];
        }
        __syncthreads();
        if (more) {
            CONV_ST;
            __syncthreads();
        }
    }

    #pragma unroll
    for (int i = 0; i < 8; ++i) {
        int co = co0 + tco4 + (i & 3) + ((i >> 2) * 64);
        float bias = bconv[co];
        float4 r0, r1;
        r0.x = fmaxf(acc[i][0] + bias, 0.f);
        r0.y = fmaxf(acc[i][1] + bias, 0.f);
        r0.z = fmaxf(acc[i][2] + bias, 0.f);
        r0.w = fmaxf(acc[i][3] + bias, 0.f);
        r1.x = fmaxf(acc[i][4] + bias, 0.f);
        r1.y = fmaxf(acc[i][5] + bias, 0.f);
        r1.z = fmaxf(acc[i][6] + bias, 0.f);
        r1.w = fmaxf(acc[i][7] + bias, 0.f);
        float* xp = &x[((size_t)(b * COUT + co) << 13) + p0 + tp4];
        *(float4*)xp = r0;
        *(float4*)(xp + 64) = r1;
    }
}

// ---------------- heads GEMM + score/box epilogue + fused score histogram ----------------
// LDS union: GEMM uses sm[0,4096) = x-chunk [ch32][pt128], sm[4096,6656) = W
// chunk; epilogue reuses sm[0,10240) as exchange -> LDS block 66->40 KB.
// Named-register prefetch of next cc-chunk (4 float4 x + 10 scalar W) hides
// the per-chunk global-load latency at low occupancy. Accumulation order
// (cc asc, kk 0..31, same FMA sequence) bitwise-unchanged vs R12.
#define HLD(CC) do {                                                            \
    const float* xb_ = &x[((size_t)(b * COUT + (CC) + ch0) << 13) + p0 + pt4];  \
    px0 = *(const float4*)&xb_[0];                                              \
    px1 = *(const float4*)&xb_[8  << 13];                                       \
    px2 = *(const float4*)&xb_[16 << 13];                                       \
    px3 = *(const float4*)&xb_[24 << 13];                                       \
    const float* wb_ = &Wht[(CC) * 80 + tid];                                   \
    ph0 = wb_[0];   ph1 = wb_[256]; ph2 = wb_[512];  ph3 = wb_[768];            \
    ph4 = wb_[1024]; ph5 = wb_[1280]; ph6 = wb_[1536]; ph7 = wb_[1792];         \
    ph8 = wb_[2048]; ph9 = wb_[2304];                                           \
} while (0)

#define HST do {                                                                \
    *(float4*)&sm[(ch0 + 0)  * 128 + pt4] = px0;                                \
    *(float4*)&sm[(ch0 + 8)  * 128 + pt4] = px1;                                \
    *(float4*)&sm[(ch0 + 16) * 128 + pt4] = px2;                                \
    *(float4*)&sm[(ch0 + 24) * 128 + pt4] = px3;                                \
    sm[4096 + tid]        = ph0; sm[4096 + tid + 256]  = ph1;                   \
    sm[4096 + tid + 512]  = ph2; sm[4096 + tid + 768]  = ph3;                   \
    sm[4096 + tid + 1024] = ph4; sm[4096 + tid + 1280] = ph5;                   \
    sm[4096 + tid + 1536] = ph6; sm[4096 + tid + 1792] = ph7;                   \
    sm[4096 + tid + 2048] = ph8; sm[4096 + tid + 2304] = ph9;                   \
} while (0)

__global__ __launch_bounds__(256) void k_heads(const float* __restrict__ x,
                                               const float* __restrict__ Wht,
                                               const float* __restrict__ bcls,
                                               const float* __restrict__ bbb,
                                               const float* __restrict__ iminfo,
                                               float* __restrict__ scores,
                                               float* __restrict__ boxes,
                                               unsigned int* __restrict__ hist) {
    __shared__ __align__(16) float sm[10240];    // 40 KB (union: GEMM / exchange)
    const int tid = threadIdx.x;
    const int p0  = blockIdx.x * 128;
    const int b   = blockIdx.y;
    const int pl  = tid & 31;     // 32 point-lanes, 4 consecutive points each
    const int og  = tid >> 5;     // 8 output groups of 9
    const int ch0 = tid >> 5;     // staging: channel base, +8i
    const int pt4 = (tid & 31) * 4;

    float acc[4][9] = {};
    float4 px0, px1, px2, px3;
    float  ph0, ph1, ph2, ph3, ph4, ph5, ph6, ph7, ph8, ph9;

    HLD(0);
    for (int cc = 0; cc < 512; cc += 32) {
        __syncthreads();          // prior chunk's readers done
        HST;
        __syncthreads();          // staging visible
        if (cc + 32 < 512) HLD(cc + 32);   // next chunk's globals in flight
        for (int kk = 0; kk < 32; ++kk) {
            float4 a4 = *(const float4*)&sm[kk * 128 + pl * 4];
            const float* wp = &sm[4096 + kk * 80 + og * 10];
            float2 w0 = *(const float2*)(wp);
            float2 w1 = *(const float2*)(wp + 2);
            float2 w2 = *(const float2*)(wp + 4);
            float2 w3 = *(const float2*)(wp + 6);
            float  w8 = wp[8];
            float wv[9] = {w0.x, w0.y, w1.x, w1.y, w2.x, w2.y, w3.x, w3.y, w8};
            #pragma unroll
            for (int k = 0; k < 9; ++k) {
                float wk = wv[k];
                acc[0][k] += a4.x * wk;
                acc[1][k] += a4.y * wk;
                acc[2][k] += a4.z * wk;
                acc[3][k] += a4.w * wk;
            }
        }
    }

    __syncthreads();
    // exchange (reuses sm): every thread writes its 4 points x 9 outputs
    #pragma unroll
    for (int pi = 0; pi < 4; ++pi)
        #pragma unroll
        for (int k = 0; k < 9; ++k)
            sm[(pl * 4 + pi) * 80 + og * 10 + k] = acc[pi][k];
    __syncthreads();

    if (tid < 128) {
        const int p = p0 + tid;
        float v[72];
        #pragma unroll
        for (int og2 = 0; og2 < 8; ++og2)
            #pragma unroll
            for (int k = 0; k < 9; ++k)
                v[og2 * 9 + k] = sm[tid * 80 + og2 * 10 + k];

        const float im0 = iminfo[b * 3 + 0], im1 = iminfo[b * 3 + 1], im2 = iminfo[b * 3 + 2];
        const float hix = im2 - 1.f, hiy = im1 - 1.f, hiz = im0 - 1.f;
        const int d = p >> 10, h = (p >> 5) & 31, w = p & 31;
        const float sx = w * 8.f, sy = h * 8.f, sz = d * 8.f;

        #pragma unroll 1
        for (int a = 0; a < 9; ++a) {
            float c0 = v[a] + bcls[a];
            float c1 = v[9 + a] + bcls[9 + a];
            float m  = fmaxf(c0, c1);
            float e0 = expf(c0 - m), e1 = expf(c1 - m);
            float sc = e1 / (e0 + e1);
            scores[b * NANCH + p * 9 + a] = sc;
            atomicAdd(&hist[b * 65536 + (__float_as_uint(sc) >> 16)], 1u);

            float aw = (float)(32 << (a % 3));                 // x,y size = 8*SCALES
            float ad = aw * 0.5f * (float)(1 << (a / 3));      // z size = aw*RATIOS
            float ax1 = sx + 3.5f - 0.5f * (aw - 1.f);
            float ax2 = sx + 3.5f + 0.5f * (aw - 1.f);
            float ay1 = sy + 3.5f - 0.5f * (aw - 1.f);
            float ay2 = sy + 3.5f + 0.5f * (aw - 1.f);
            float az1 = sz + 3.5f - 0.5f * (ad - 1.f);
            float az2 = sz + 3.5f + 0.5f * (ad - 1.f);
            float ww_ = ax2 - ax1 + 1.f, hh_ = ay2 - ay1 + 1.f, dd_ = az2 - az1 + 1.f;
            float cx = ax1 + 0.5f * ww_, cy = ay1 + 0.5f * hh_, cz = az1 + 0.5f * dd_;

            const float* dv = &v[18 + a * 6];
            float dx = dv[0] + bbb[a * 6 + 0];
            float dy = dv[1] + bbb[a * 6 + 1];
            float dz = dv[2] + bbb[a * 6 + 2];
            float dw = dv[3] + bbb[a * 6 + 3];
            float dh = dv[4] + bbb[a * 6 + 4];
            float dd2 = dv[5] + bbb[a * 6 + 5];
            float pcx = dx * ww_ + cx, pcy = dy * hh_ + cy, pcz = dz * dd_ + cz;
            float pw = expf(dw) * ww_, ph = expf(dh) * hh_, pd = expf(dd2) * dd_;
            float x1 = fminf(fmaxf(pcx - 0.5f * pw, 0.f), hix);
            float y1 = fminf(fmaxf(pcy - 0.5f * ph, 0.f), hiy);
            float z1 = fminf(fmaxf(pcz - 0.5f * pd, 0.f), hiz);
            float x2 = fminf(fmaxf(pcx + 0.5f * pw, 0.f), hix);
            float y2 = fminf(fmaxf(pcy + 0.5f * ph, 0.f), hiy);
            float z2 = fminf(fmaxf(pcz + 0.5f * pd, 0.f), hiz);
            float* bp = &boxes[(size_t)(b * NANCH + p * 9 + a) * 6];
            bp[0] = x1; bp[1] = y1; bp[2] = z1; bp[3] = x2; bp[4] = y2; bp[5] = z2;
        }
    }
}

// ---------------- fused cutoff + compact (one block per batch) ----------------
__global__ __launch_bounds__(1024) void k_cutcompact(const float* __restrict__ scores,
                                                     const unsigned int* __restrict__ hist,
                                                     unsigned long long* __restrict__ cand) {
    __shared__ unsigned int cs[1024], scan[1024];
    __shared__ unsigned int sh_cut, sh_pos;
    const int b = blockIdx.x, tid = threadIdx.x;
    const unsigned int* h = hist + b * 65536;
    unsigned int s = 0;
    for (int i = 0; i < 64; ++i) s += h[tid * 64 + i];
    cs[tid] = s; scan[tid] = s;
    if (tid == 0) sh_pos = 0;
    __syncthreads();
    for (int d = 1; d < 1024; d <<= 1) {           // scan[c] -> sum_{c'>=c} cs[c']
        unsigned int v = scan[tid];
        unsigned int add = (tid + d < 1024) ? scan[tid + d] : 0u;
        __syncthreads();
        scan[tid] = v + add;
        __syncthreads();
    }
    unsigned int above = (tid + 1 < 1024) ? scan[tid + 1] : 0u;   // strictly above this chunk
    if (above < PRE && above + cs[tid] >= PRE) {   // exactly one thread
        unsigned int cum = above;
        for (int x = tid * 64 + 63; x >= tid * 64; --x) {
            cum += h[x];
            if (cum >= PRE) { sh_cut = (unsigned int)x; break; }
        }
    }
    __syncthreads();
    const unsigned int cut = sh_cut;
    const float* sc = scores + b * NANCH;
    for (int i = tid; i < NANCH; i += 1024) {
        unsigned int u = __float_as_uint(sc[i]);
        if ((u >> 16) >= cut) {
            unsigned int pos = atomicAdd(&sh_pos, 1u);
            if (pos < CAP) cand[b * CAP + pos] = ((unsigned long long)(~u) << 32) | (unsigned)i;
        }
    }
    __syncthreads();
    const unsigned int cnt = (sh_pos < CAP) ? sh_pos : CAP;
    for (int i = (int)cnt + tid; i < CAP; i += 1024)
        cand[b * CAP + i] = ~0ull;
}

// bitonic sort CAP keys asc (key = ~score_bits || idx => score desc, idx asc);
// first 2048 are the sorted top-2048; gather their boxes.
__global__ __launch_bounds__(1024) void k_sort2(const unsigned long long* __restrict__ cand,
                                                const float* __restrict__ boxes,
                                                float* __restrict__ sboxes) {
    __shared__ unsigned long long sk[CAP];
    const int b = blockIdx.x, tid = threadIdx.x;
    for (int i = tid; i < CAP; i += 1024) sk[i] = cand[b * CAP + i];
    __syncthreads();
    for (int k = 2; k <= CAP; k <<= 1) {
        for (int j = k >> 1; j > 0; j >>= 1) {
            #pragma unroll 1
            for (int i = tid; i < CAP; i += 1024) {
                int ixj = i ^ j;
                if (ixj > i) {
                    unsigned long long va = sk[i], vb = sk[ixj];
                    bool up = ((i & k) == 0);
                    if ((va > vb) == up) { sk[i] = vb; sk[ixj] = va; }
                }
            }
            __syncthreads();
        }
    }
    for (int r = tid; r < PRE; r += 1024) {
        unsigned int n = (unsigned int)(sk[r] & 0xFFFFFFFFull);
        const float* src = &boxes[(size_t)(b * NANCH + (int)n) * 6];
        float* dst = &sboxes[(size_t)(b * PRE + r) * 6];
        #pragma unroll
        for (int c = 0; c < 6; ++c) dst[c] = src[c];
    }
}

// suppression bitmask (upper triangle only): mask[b][i][w] bit j <=> j>i && IoU>0.7
__global__ __launch_bounds__(256) void k_mask(const float* __restrict__ sboxes,
                                              unsigned long long* __restrict__ mask) {
    if (blockIdx.y < blockIdx.x) return;   // j0 < i0: never read (k_nms gates by word)
    __shared__ float rb[64 * 6], cb[64 * 6];
    const int i0 = blockIdx.x * 64, j0 = blockIdx.y * 64, b = blockIdx.z;
    const int tid = threadIdx.x;
    for (int e = tid; e < 384; e += 256) {
        rb[e] = sboxes[(size_t)(b * PRE + i0) * 6 + e];
        cb[e] = sboxes[(size_t)(b * PRE + j0) * 6 + e];
    }
    __syncthreads();
    const int wave = tid >> 6, lane = tid & 63;
    const float bx1 = cb[lane * 6 + 0], by1 = cb[lane * 6 + 1], bz1 = cb[lane * 6 + 2];
    const float bx2 = cb[lane * 6 + 3], by2 = cb[lane * 6 + 4], bz2 = cb[lane * 6 + 5];
    const float vb = (bx2 - bx1 + 1.f) * (by2 - by1 + 1.f) * (bz2 - bz1 + 1.f);
    const int j = j0 + lane;
    for (int rr = 0; rr < 16; ++rr) {
        const int il = wave * 16 + rr;
        const int i = i0 + il;
        float ax1 = rb[il * 6 + 0], ay1 = rb[il * 6 + 1], az1 = rb[il * 6 + 2];
        float ax2 = rb[il * 6 + 3], ay2 = rb[il * 6 + 4], az2 = rb[il * 6 + 5];
        float va = (ax2 - ax1 + 1.f) * (ay2 - ay1 + 1.f) * (az2 - az1 + 1.f);
        float ix = fmaxf(fminf(ax2, bx2) - fmaxf(ax1, bx1) + 1.f, 0.f);
        float iy = fmaxf(fminf(ay2, by2) - fmaxf(ay1, by1) + 1.f, 0.f);
        float iz = fmaxf(fminf(az2, bz2) - fmaxf(az1, bz1) + 1.f, 0.f);
        float inter = ix * iy * iz;
        float iou = inter / (va + vb - inter);
        bool bit = (j > i) && (iou > NMS_TH);
        unsigned long long word = __ballot(bit);
        if (lane == 0) mask[(size_t)(b * PRE + i) * 32 + (j0 >> 6)] = word;
    }
}

// single-wave greedy NMS scan + ROI output; 8-deep mask-row prefetch.
__global__ __launch_bounds__(64) void k_nms(const unsigned long long* __restrict__ mask,
                                            const float* __restrict__ sboxes,
                                            float* __restrict__ out) {
    const int b = blockIdx.x, lane = threadIdx.x;
    __shared__ int sel[POST];
    unsigned long long keep = ~0ull;          // lane l<32 owns bits [64l,64l+64)
    const int lw = lane & 31;
    const unsigned long long* mrow = mask + (size_t)b * PRE * 32 + lw;
    unsigned long long b0 = mrow[0 * 32], b1 = mrow[1 * 32], b2 = mrow[2 * 32], b3 = mrow[3 * 32];
    unsigned long long b4 = mrow[4 * 32], b5 = mrow[5 * 32], b6 = mrow[6 * 32], b7 = mrow[7 * 32];
    int kcount = 0;

#define NMS_STEP(J, BUF)                                                        \
    {                                                                           \
        int i = i0 + (J);                                                       \
        unsigned long long cur = (lw >= (i >> 6)) ? BUF : 0ull;                 \
        int nr = i0 + 8 + (J);                                                  \
        BUF = (nr < PRE) ? mrow[(size_t)nr * 32] : 0ull;                        \
        unsigned long long kw = __shfl(keep, i >> 6);                           \
        if ((kw >> (i & 63)) & 1ull) {                                          \
            if (lane < 32) keep &= ~cur;                                        \
            if (lane == 0 && kcount < POST) sel[kcount] = i;                    \
            ++kcount;                                                           \
            if (kcount >= POST) goto nms_done;                                  \
        }                                                                       \
    }

    for (int i0 = 0; i0 < PRE; i0 += 8) {
        NMS_STEP(0, b0) NMS_STEP(1, b1) NMS_STEP(2, b2) NMS_STEP(3, b3)
        NMS_STEP(4, b4) NMS_STEP(5, b5) NMS_STEP(6, b6) NMS_STEP(7, b7)
    }
nms_done:
    __syncthreads();
    const int kc = kcount;
    for (int r = lane; r < POST; r += 64) {
        float* op = &out[(size_t)(b * POST + r) * 7];
        op[0] = (float)b;
        if (r < kc) {
            const float* sb = &sboxes[(size_t)(b * PRE + sel[r]) * 6];
            #pragma unroll
            for (int c = 0; c < 6; ++c) op[1 + c] = sb[c];
        } else {
            #pragma unroll
            for (int c = 0; c < 6; ++c) op[1 + c] = 0.f;
        }
    }
#undef NMS_STEP
}

extern "C" void kernel_launch(void* const* d_in, const int* in_sizes, int n_in,
                              void* d_out, int out_size, void* d_ws, size_t ws_size,
                              hipStream_t stream) {
    const float* base_feat = (const float*)d_in[0];
    const float* im_info   = (const float*)d_in[1];
    const float* W_conv    = (const float*)d_in[4];
    const float* b_conv    = (const float*)d_in[5];
    const float* W_cls     = (const float*)d_in[6];
    const float* b_cls     = (const float*)d_in[7];
    const float* W_bbox    = (const float*)d_in[8];
    const float* b_bbox    = (const float*)d_in[9];

    char* ws = (char*)d_ws;
    float* Wt      = (float*)(ws + OFF_WT);
    float* Wht     = (float*)(ws + OFF_WHT);
    float* x       = (float*)(ws + OFF_X);
    float* scores  = (float*)(ws + OFF_SC);
    float* boxes   = (float*)(ws + OFF_BX);
    float* sboxes  = (float*)(ws + OFF_SB);
    unsigned long long* mask = (unsigned long long*)(ws + OFF_MK);
    unsigned int* hist = (unsigned int*)(ws + OFF_HIST);
    unsigned long long* cand = (unsigned long long*)(ws + OFF_CAND);

    const int NTRANS = NT_WT + NT_WHT;
    k_wtrans<<<(NTRANS + 255) / 256, 256, 0, stream>>>(W_conv, Wt, W_cls, W_bbox, Wht);
    k_conv<<<dim3(64, 4, 2), 256, 0, stream>>>(base_feat, Wt, b_conv, x);
    // Wt region dead now; zero hist (aliases Wt) AFTER k_conv, before k_heads.
    hipMemsetAsync(hist, 0, BATCH * 65536 * sizeof(unsigned int), stream);
    k_heads<<<dim3(64, 2), 256, 0, stream>>>(x, Wht, b_cls, b_bbox, im_info, scores, boxes, hist);
    k_cutcompact<<<BATCH, 1024, 0, stream>>>(scores, hist, cand);
    k_sort2<<<BATCH, 1024, 0, stream>>>(cand, boxes, sboxes);
    k_mask<<<dim3(32, 32, 2), 256, 0, stream>>>(sboxes, mask);
    k_nms<<<BATCH, 64, 0, stream>>>(mask, sboxes, (float*)d_out);
}

// Round 14
// 1028.797 us; speedup vs baseline: 1.0227x; 1.0227x over previous
//
#include <hip/hip_runtime.h>
#include <hip/hip_bf16.h>
#include <stdint.h>

// Problem constants
#define BATCH 2
#define CIN 128
#define COUT 512
#define DD 8
#define PSPAT 8192          // D*H*W
#define NA 9                // anchors per position
#define NANCH 73728         // PSPAT*NA
#define PRE 2048
#define POST 300
#define CAP 4096            // candidate buffer (top-2048 + cutoff-bin ties)
#define NMS_TH 0.7f

// ws layout (byte offsets). Selection scratch aliases the Wt region, which is
// DEAD ONLY AFTER k_conv: hist is zeroed after k_conv (R10: zeroing it inside
// k_wtrans raced with Wt writes -> corrupted weights).
constexpr size_t OFF_WT   = 0;          // 27*128*512 f32   = 7,077,888 B
constexpr size_t OFF_WHT  = 7077888;    // 512*80 f32       = 163,840 B
constexpr size_t OFF_X    = 7241728;    // 2*512*8192 f32   = 33,554,432 B
constexpr size_t OFF_SC   = 40796160;   // 2*73728 f32      = 589,824 B
constexpr size_t OFF_BX   = 41385984;   // 2*73728*6 f32    = 3,538,944 B
constexpr size_t OFF_SB   = 44957696;   // 2*2048*6 f32     = 98,304 B
constexpr size_t OFF_MK   = 45056000;   // 2*2048*32 u64    = 1,048,576 B  (end 46,104,576)
// selection scratch inside [0, OFF_WT+7MB), used only after k_conv:
constexpr size_t OFF_HIST = 16;              // 2*65536 u32 = 524,288 B
constexpr size_t OFF_CAND = 524304;          // 2*4096 u64  = 65,536 B

// ---------------- fused weight transforms (one launch) ----------------
// Wht[c][q], q = og*10 + k (k<9 real), output o = og*9 + k  (8 groups of 9)
#define NT_WT   (27 * 128 * 512)
#define NT_WHT  (512 * 80)
__global__ void k_wtrans(const float* __restrict__ Wc, float* __restrict__ Wt,
                         const float* __restrict__ Wcls, const float* __restrict__ Wbb,
                         float* __restrict__ Wht) {
    int e = blockIdx.x * blockDim.x + threadIdx.x;
    if (e < NT_WT) {
        int co  = e & 511;
        int ci  = (e >> 9) & 127;
        int tap = e >> 16;
        Wt[e] = Wc[(co * 128 + ci) * 27 + tap];
        return;
    }
    e -= NT_WT;
    if (e >= NT_WHT) return;
    int q = e % 80;
    int c = e / 80;
    int og = q / 10, k = q % 10;
    int o = og * 9 + k;
    float v = 0.f;
    if (k < 9) v = (o < 18) ? Wcls[o * 512 + c] : Wbb[(o - 18) * 512 + c];
    Wht[e] = v;
}

// ---------------- conv3d 3x3x3 + bias + relu (implicit GEMM, fp32) ----------------
// FROZEN (R11/R12): at the LDS-throughput roofline for 8x8 frag / 256 thr /
// 128x128 tile (VALU 60-62% vs 67% analytic LDS cap). Named-float4 register
// prefetch (arrays always went to scratch/LDS; named vars are the only
// guaranteed-VGPR form). Stage order tap(asc valid range)->ci(0..127).

#define LDA4(J, V)                                                              \
    V.x = ok_ ? inb_[(size_t)(4 * (J) + 0) * 16384] : 0.f;                      \
    V.y = ok_ ? inb_[(size_t)(4 * (J) + 1) * 16384] : 0.f;                      \
    V.z = ok_ ? inb_[(size_t)(4 * (J) + 2) * 16384] : 0.f;                      \
    V.w = ok_ ? inb_[(size_t)(4 * (J) + 3) * 16384] : 0.f;

#define LDB4(J, V) V = *(const float4*)&wr_[(size_t)(kkB0 + 8 * (J)) * 512 + c4];

#define CONV_LD(S) do {                                                         \
    const int tap_ = tapBase + ((S) >> 1);                                      \
    const int cc_  = ((S) & 1) << 6;                                            \
    const int kd_ = tap_ / 9, kh_ = (tap_ / 3) % 3, kw_ = tap_ % 3;             \
    const int id_ = d0 + kd_ - 1;                                               \
    const int h_  = h0 + (spc >> 5) + kh_ - 1;                                  \
    const int w_  = (spc & 31) + kw_ - 1;                                       \
    const bool ok_ = ((unsigned)h_ < 32u) && ((unsigned)w_ < 32u);              \
    const float* inb_ = in + (((size_t)((b * CIN + cc_ + kkA0) * DD + id_)) << 10) \
                           + (h_ << 5) + w_;                                    \
    const float* wr_ = Wt + (size_t)(tap_ * 128 + cc_) * 512 + co0;             \
    LDA4(0, pa0) LDA4(1, pa1) LDA4(2, pa2) LDA4(3, pa3)                         \
    LDA4(4, pa4) LDA4(5, pa5) LDA4(6, pa6) LDA4(7, pa7)                         \
    LDB4(0, pw0) LDB4(1, pw1) LDB4(2, pw2) LDB4(3, pw3)                         \
    LDB4(4, pw4) LDB4(5, pw5) LDB4(6, pw6) LDB4(7, pw7)                         \
} while (0)

#define STA4(J, V)                                                              \
    As[(kkA0 + 2 * (4 * (J) + 0)) * 128 + spc] = V.x;                           \
    As[(kkA0 + 2 * (4 * (J) + 1)) * 128 + spc] = V.y;                           \
    As[(kkA0 + 2 * (4 * (J) + 2)) * 128 + spc] = V.z;                           \
    As[(kkA0 + 2 * (4 * (J) + 3)) * 128 + spc] = V.w;

#define STB4(J, V) *(float4*)&Bs[(kkB0 + 8 * (J)) * 128 + c4] = V;

#define CONV_ST do {                                                            \
    STA4(0, pa0) STA4(1, pa1) STA4(2, pa2) STA4(3, pa3)                         \
    STA4(4, pa4) STA4(5, pa5) STA4(6, pa6) STA4(7, pa7)                         \
    STB4(0, pw0) STB4(1, pw1) STB4(2, pw2) STB4(3, pw3)                         \
    STB4(4, pw4) STB4(5, pw5) STB4(6, pw6) STB4(7, pw7)                         \
} while (0)

__global__ __launch_bounds__(256, 2) void k_conv(const float* __restrict__ in,
                                                 const float* __restrict__ Wt,
                                                 const float* __restrict__ bconv,
                                                 float* __restrict__ x) {
    __shared__ __align__(16) float As[64 * 128];   // 32 KB
    __shared__ __align__(16) float Bs[64 * 128];   // 32 KB
    const int tid  = threadIdx.x;
    const int p0   = blockIdx.x * 128;   // spatial tile: fixed d, 4 h-rows
    const int co0  = blockIdx.y * 128;
    const int b    = blockIdx.z;
    const int d0   = p0 >> 10;
    const int h0   = (p0 >> 5) & 31;
    const int tp4  = (tid & 15) * 4;     // spatial frag base
    const int tco4 = (tid >> 4) * 4;     // cout frag base

    const int tapBase = (d0 == 0) ? 9 : 0;
    const int nTap    = 27 - (((d0 == 0) || (d0 == 7)) ? 9 : 0);
    const int NST     = nTap * 2;        // stages = taps x 2 ci-chunks of 64

    const int spc  = tid & 127;          // A: sp column
    const int kkA0 = tid >> 7;           // A: kk = kkA0 + 2i
    const int kkB0 = tid >> 5;           // B: kk = kkB0 + 8j
    const int c4   = (tid & 31) * 4;     // B: co within row

    float acc[8][8] = {};
    float4 pa0, pa1, pa2, pa3, pa4, pa5, pa6, pa7;   // A prefetch (32 floats)
    float4 pw0, pw1, pw2, pw3, pw4, pw5, pw6, pw7;   // B prefetch (8 float4)

    CONV_LD(0);
    CONV_ST;
    __syncthreads();

    for (int s = 0; s < NST; ++s) {
        const bool more = (s + 1 < NST);
        if (more) CONV_LD(s + 1);        // loads in flight during compute
        #pragma unroll 2
        for (int kk = 0; kk < 64; ++kk) {
            float4 a0 = *(const float4*)&As[kk * 128 + tp4];
            float4 a1 = *(const float4*)&As[kk * 128 + tp4 + 64];
            float4 b0 = *(const float4*)&Bs[kk * 128 + tco4];
            float4 b1 = *(const float4*)&Bs[kk * 128 + tco4 + 64];
            float av[8] = {a0.x, a0.y, a0.z, a0.w, a1.x, a1.y, a1.z, a1.w};
            float bv[8] = {b0.x, b0.y, b0.z, b0.w, b1.x, b1.y, b1.z, b1.w};
            #pragma unroll
            for (int i = 0; i < 8; ++i)
                #pragma unroll
                for (int j = 0; j < 8; ++j)
                    acc[i][j] += bv[i] * av[j];
        }
        __syncthreads();
        if (more) {
            CONV_ST;
            __syncthreads();
        }
    }

    #pragma unroll
    for (int i = 0; i < 8; ++i) {
        int co = co0 + tco4 + (i & 3) + ((i >> 2) * 64);
        float bias = bconv[co];
        float4 r0, r1;
        r0.x = fmaxf(acc[i][0] + bias, 0.f);
        r0.y = fmaxf(acc[i][1] + bias, 0.f);
        r0.z = fmaxf(acc[i][2] + bias, 0.f);
        r0.w = fmaxf(acc[i][3] + bias, 0.f);
        r1.x = fmaxf(acc[i][4] + bias, 0.f);
        r1.y = fmaxf(acc[i][5] + bias, 0.f);
        r1.z = fmaxf(acc[i][6] + bias, 0.f);
        r1.w = fmaxf(acc[i][7] + bias, 0.f);
        float* xp = &x[((size_t)(b * COUT + co) << 13) + p0 + tp4];
        *(float4*)xp = r0;
        *(float4*)(xp + 64) = r1;
    }
}

// ---------------- heads GEMM + score/box epilogue + fused score histogram ----------------
// R12 form (measured best): 128-point tile, 8 og-groups of 9, vectorized weight
// reads, separate smx/Whs/ex buffers (no prefetch -- R13's prefetch+union
// variant added 9.5e5 bank conflicts and regressed 14us).
__global__ __launch_bounds__(256) void k_heads(const float* __restrict__ x,
                                               const float* __restrict__ Wht,
                                               const float* __restrict__ bcls,
                                               const float* __restrict__ bbb,
                                               const float* __restrict__ iminfo,
                                               float* __restrict__ scores,
                                               float* __restrict__ boxes,
                                               unsigned int* __restrict__ hist) {
    __shared__ __align__(16) float smx[4096];    // x chunk [ch32][pt128]  16 KB
    __shared__ __align__(16) float Whs[2560];    // weight chunk [kk32][80] 10 KB
    __shared__ __align__(16) float ex[10240];    // exchange [pt128][80]    40 KB
    const int tid = threadIdx.x;
    const int p0  = blockIdx.x * 128;
    const int b   = blockIdx.y;
    const int pl  = tid & 31;     // 32 point-lanes, 4 consecutive points each
    const int og  = tid >> 5;     // 8 output groups of 9

    float acc[4][9] = {};

    for (int cc = 0; cc < 512; cc += 32) {
        __syncthreads();
        #pragma unroll
        for (int i = 0; i < 4; ++i) {
            int e4 = tid + i * 256;          // 1024 float4s
            int ch = e4 >> 5;
            int pt4 = (e4 & 31) * 4;
            *(float4*)&smx[ch * 128 + pt4] =
                *(const float4*)&x[((size_t)(b * COUT + cc + ch) << 13) + p0 + pt4];
        }
        #pragma unroll
        for (int i = 0; i < 10; ++i) {
            int e = tid + i * 256;
            Whs[e] = Wht[cc * 80 + e];
        }
        __syncthreads();
        for (int kk = 0; kk < 32; ++kk) {
            float4 a4 = *(const float4*)&smx[kk * 128 + pl * 4];
            const float* wp = &Whs[kk * 80 + og * 10];
            float2 w0 = *(const float2*)(wp);
            float2 w1 = *(const float2*)(wp + 2);
            float2 w2 = *(const float2*)(wp + 4);
            float2 w3 = *(const float2*)(wp + 6);
            float  w8 = wp[8];
            float wv[9] = {w0.x, w0.y, w1.x, w1.y, w2.x, w2.y, w3.x, w3.y, w8};
            #pragma unroll
            for (int k = 0; k < 9; ++k) {
                float wk = wv[k];
                acc[0][k] += a4.x * wk;
                acc[1][k] += a4.y * wk;
                acc[2][k] += a4.z * wk;
                acc[3][k] += a4.w * wk;
            }
        }
    }

    __syncthreads();
    // exchange: every thread writes its 4 points x 9 outputs
    #pragma unroll
    for (int pi = 0; pi < 4; ++pi)
        #pragma unroll
        for (int k = 0; k < 9; ++k)
            ex[(pl * 4 + pi) * 80 + og * 10 + k] = acc[pi][k];
    __syncthreads();

    if (tid < 128) {
        const int p = p0 + tid;
        float v[72];
        #pragma unroll
        for (int og2 = 0; og2 < 8; ++og2)
            #pragma unroll
            for (int k = 0; k < 9; ++k)
                v[og2 * 9 + k] = ex[tid * 80 + og2 * 10 + k];

        const float im0 = iminfo[b * 3 + 0], im1 = iminfo[b * 3 + 1], im2 = iminfo[b * 3 + 2];
        const float hix = im2 - 1.f, hiy = im1 - 1.f, hiz = im0 - 1.f;
        const int d = p >> 10, h = (p >> 5) & 31, w = p & 31;
        const float sx = w * 8.f, sy = h * 8.f, sz = d * 8.f;

        #pragma unroll 1
        for (int a = 0; a < 9; ++a) {
            float c0 = v[a] + bcls[a];
            float c1 = v[9 + a] + bcls[9 + a];
            float m  = fmaxf(c0, c1);
            float e0 = expf(c0 - m), e1 = expf(c1 - m);
            float sc = e1 / (e0 + e1);
            scores[b * NANCH + p * 9 + a] = sc;
            atomicAdd(&hist[b * 65536 + (__float_as_uint(sc) >> 16)], 1u);

            float aw = (float)(32 << (a % 3));                 // x,y size = 8*SCALES
            float ad = aw * 0.5f * (float)(1 << (a / 3));      // z size = aw*RATIOS
            float ax1 = sx + 3.5f - 0.5f * (aw - 1.f);
            float ax2 = sx + 3.5f + 0.5f * (aw - 1.f);
            float ay1 = sy + 3.5f - 0.5f * (aw - 1.f);
            float ay2 = sy + 3.5f + 0.5f * (aw - 1.f);
            float az1 = sz + 3.5f - 0.5f * (ad - 1.f);
            float az2 = sz + 3.5f + 0.5f * (ad - 1.f);
            float ww_ = ax2 - ax1 + 1.f, hh_ = ay2 - ay1 + 1.f, dd_ = az2 - az1 + 1.f;
            float cx = ax1 + 0.5f * ww_, cy = ay1 + 0.5f * hh_, cz = az1 + 0.5f * dd_;

            const float* dv = &v[18 + a * 6];
            float dx = dv[0] + bbb[a * 6 + 0];
            float dy = dv[1] + bbb[a * 6 + 1];
            float dz = dv[2] + bbb[a * 6 + 2];
            float dw = dv[3] + bbb[a * 6 + 3];
            float dh = dv[4] + bbb[a * 6 + 4];
            float dd2 = dv[5] + bbb[a * 6 + 5];
            float pcx = dx * ww_ + cx, pcy = dy * hh_ + cy, pcz = dz * dd_ + cz;
            float pw = expf(dw) * ww_, ph = expf(dh) * hh_, pd = expf(dd2) * dd_;
            float x1 = fminf(fmaxf(pcx - 0.5f * pw, 0.f), hix);
            float y1 = fminf(fmaxf(pcy - 0.5f * ph, 0.f), hiy);
            float z1 = fminf(fmaxf(pcz - 0.5f * pd, 0.f), hiz);
            float x2 = fminf(fmaxf(pcx + 0.5f * pw, 0.f), hix);
            float y2 = fminf(fmaxf(pcy + 0.5f * ph, 0.f), hiy);
            float z2 = fminf(fmaxf(pcz + 0.5f * pd, 0.f), hiz);
            float* bp = &boxes[(size_t)(b * NANCH + p * 9 + a) * 6];
            bp[0] = x1; bp[1] = y1; bp[2] = z1; bp[3] = x2; bp[4] = y2; bp[5] = z2;
        }
    }
}

// ---------------- fused cutoff + compact (one block per batch) ----------------
__global__ __launch_bounds__(1024) void k_cutcompact(const float* __restrict__ scores,
                                                     const unsigned int* __restrict__ hist,
                                                     unsigned long long* __restrict__ cand) {
    __shared__ unsigned int cs[1024], scan[1024];
    __shared__ unsigned int sh_cut, sh_pos;
    const int b = blockIdx.x, tid = threadIdx.x;
    const unsigned int* h = hist + b * 65536;
    unsigned int s = 0;
    for (int i = 0; i < 64; ++i) s += h[tid * 64 + i];
    cs[tid] = s; scan[tid] = s;
    if (tid == 0) sh_pos = 0;
    __syncthreads();
    for (int d = 1; d < 1024; d <<= 1) {           // scan[c] -> sum_{c'>=c} cs[c']
        unsigned int v = scan[tid];
        unsigned int add = (tid + d < 1024) ? scan[tid + d] : 0u;
        __syncthreads();
        scan[tid] = v + add;
        __syncthreads();
    }
    unsigned int above = (tid + 1 < 1024) ? scan[tid + 1] : 0u;   // strictly above this chunk
    if (above < PRE && above + cs[tid] >= PRE) {   // exactly one thread
        unsigned int cum = above;
        for (int x = tid * 64 + 63; x >= tid * 64; --x) {
            cum += h[x];
            if (cum >= PRE) { sh_cut = (unsigned int)x; break; }
        }
    }
    __syncthreads();
    const unsigned int cut = sh_cut;
    const float* sc = scores + b * NANCH;
    for (int i = tid; i < NANCH; i += 1024) {
        unsigned int u = __float_as_uint(sc[i]);
        if ((u >> 16) >= cut) {
            unsigned int pos = atomicAdd(&sh_pos, 1u);
            if (pos < CAP) cand[b * CAP + pos] = ((unsigned long long)(~u) << 32) | (unsigned)i;
        }
    }
    __syncthreads();
    const unsigned int cnt = (sh_pos < CAP) ? sh_pos : CAP;
    for (int i = (int)cnt + tid; i < CAP; i += 1024)
        cand[b * CAP + i] = ~0ull;
}

// bitonic sort CAP keys asc (key = ~score_bits || idx => score desc, idx asc);
// first 2048 are the sorted top-2048; gather their boxes.
__global__ __launch_bounds__(1024) void k_sort2(const unsigned long long* __restrict__ cand,
                                                const float* __restrict__ boxes,
                                                float* __restrict__ sboxes) {
    __shared__ unsigned long long sk[CAP];
    const int b = blockIdx.x, tid = threadIdx.x;
    for (int i = tid; i < CAP; i += 1024) sk[i] = cand[b * CAP + i];
    __syncthreads();
    for (int k = 2; k <= CAP; k <<= 1) {
        for (int j = k >> 1; j > 0; j >>= 1) {
            #pragma unroll 1
            for (int i = tid; i < CAP; i += 1024) {
                int ixj = i ^ j;
                if (ixj > i) {
                    unsigned long long va = sk[i], vb = sk[ixj];
                    bool up = ((i & k) == 0);
                    if ((va > vb) == up) { sk[i] = vb; sk[ixj] = va; }
                }
            }
            __syncthreads();
        }
    }
    for (int r = tid; r < PRE; r += 1024) {
        unsigned int n = (unsigned int)(sk[r] & 0xFFFFFFFFull);
        const float* src = &boxes[(size_t)(b * NANCH + (int)n) * 6];
        float* dst = &sboxes[(size_t)(b * PRE + r) * 6];
        #pragma unroll
        for (int c = 0; c < 6; ++c) dst[c] = src[c];
    }
}

// suppression bitmask (upper triangle only): mask[b][i][w] bit j <=> j>i && IoU>0.7
__global__ __launch_bounds__(256) void k_mask(const float* __restrict__ sboxes,
                                              unsigned long long* __restrict__ mask) {
    if (blockIdx.y < blockIdx.x) return;   // j0 < i0: never read (k_nms gates by word)
    __shared__ float rb[64 * 6], cb[64 * 6];
    const int i0 = blockIdx.x * 64, j0 = blockIdx.y * 64, b = blockIdx.z;
    const int tid = threadIdx.x;
    for (int e = tid; e < 384; e += 256) {
        rb[e] = sboxes[(size_t)(b * PRE + i0) * 6 + e];
        cb[e] = sboxes[(size_t)(b * PRE + j0) * 6 + e];
    }
    __syncthreads();
    const int wave = tid >> 6, lane = tid & 63;
    const float bx1 = cb[lane * 6 + 0], by1 = cb[lane * 6 + 1], bz1 = cb[lane * 6 + 2];
    const float bx2 = cb[lane * 6 + 3], by2 = cb[lane * 6 + 4], bz2 = cb[lane * 6 + 5];
    const float vb = (bx2 - bx1 + 1.f) * (by2 - by1 + 1.f) * (bz2 - bz1 + 1.f);
    const int j = j0 + lane;
    for (int rr = 0; rr < 16; ++rr) {
        const int il = wave * 16 + rr;
        const int i = i0 + il;
        float ax1 = rb[il * 6 + 0], ay1 = rb[il * 6 + 1], az1 = rb[il * 6 + 2];
        float ax2 = rb[il * 6 + 3], ay2 = rb[il * 6 + 4], az2 = rb[il * 6 + 5];
        float va = (ax2 - ax1 + 1.f) * (ay2 - ay1 + 1.f) * (az2 - az1 + 1.f);
        float ix = fmaxf(fminf(ax2, bx2) - fmaxf(ax1, bx1) + 1.f, 0.f);
        float iy = fmaxf(fminf(ay2, by2) - fmaxf(ay1, by1) + 1.f, 0.f);
        float iz = fmaxf(fminf(az2, bz2) - fmaxf(az1, bz1) + 1.f, 0.f);
        float inter = ix * iy * iz;
        float iou = inter / (va + vb - inter);
        bool bit = (j > i) && (iou > NMS_TH);
        unsigned long long word = __ballot(bit);
        if (lane == 0) mask[(size_t)(b * PRE + i) * 32 + (j0 >> 6)] = word;
    }
}

// single-wave greedy NMS scan + ROI output; 8-deep mask-row prefetch.
__global__ __launch_bounds__(64) void k_nms(const unsigned long long* __restrict__ mask,
                                            const float* __restrict__ sboxes,
                                            float* __restrict__ out) {
    const int b = blockIdx.x, lane = threadIdx.x;
    __shared__ int sel[POST];
    unsigned long long keep = ~0ull;          // lane l<32 owns bits [64l,64l+64)
    const int lw = lane & 31;
    const unsigned long long* mrow = mask + (size_t)b * PRE * 32 + lw;
    unsigned long long b0 = mrow[0 * 32], b1 = mrow[1 * 32], b2 = mrow[2 * 32], b3 = mrow[3 * 32];
    unsigned long long b4 = mrow[4 * 32], b5 = mrow[5 * 32], b6 = mrow[6 * 32], b7 = mrow[7 * 32];
    int kcount = 0;

#define NMS_STEP(J, BUF)                                                        \
    {                                                                           \
        int i = i0 + (J);                                                       \
        unsigned long long cur = (lw >= (i >> 6)) ? BUF : 0ull;                 \
        int nr = i0 + 8 + (J);                                                  \
        BUF = (nr < PRE) ? mrow[(size_t)nr * 32] : 0ull;                        \
        unsigned long long kw = __shfl(keep, i >> 6);                           \
        if ((kw >> (i & 63)) & 1ull) {                                          \
            if (lane < 32) keep &= ~cur;                                        \
            if (lane == 0 && kcount < POST) sel[kcount] = i;                    \
            ++kcount;                                                           \
            if (kcount >= POST) goto nms_done;                                  \
        }                                                                       \
    }

    for (int i0 = 0; i0 < PRE; i0 += 8) {
        NMS_STEP(0, b0) NMS_STEP(1, b1) NMS_STEP(2, b2) NMS_STEP(3, b3)
        NMS_STEP(4, b4) NMS_STEP(5, b5) NMS_STEP(6, b6) NMS_STEP(7, b7)
    }
nms_done:
    __syncthreads();
    const int kc = kcount;
    for (int r = lane; r < POST; r += 64) {
        float* op = &out[(size_t)(b * POST + r) * 7];
        op[0] = (float)b;
        if (r < kc) {
            const float* sb = &sboxes[(size_t)(b * PRE + sel[r]) * 6];
            #pragma unroll
            for (int c = 0; c < 6; ++c) op[1 + c] = sb[c];
        } else {
            #pragma unroll
            for (int c = 0; c < 6; ++c) op[1 + c] = 0.f;
        }
    }
#undef NMS_STEP
}

extern "C" void kernel_launch(void* const* d_in, const int* in_sizes, int n_in,
                              void* d_out, int out_size, void* d_ws, size_t ws_size,
                              hipStream_t stream) {
    const float* base_feat = (const float*)d_in[0];
    const float* im_info   = (const float*)d_in[1];
    const float* W_conv    = (const float*)d_in[4];
    const float* b_conv    = (const float*)d_in[5];
    const float* W_cls     = (const float*)d_in[6];
    const float* b_cls     = (const float*)d_in[7];
    const float* W_bbox    = (const float*)d_in[8];
    const float* b_bbox    = (const float*)d_in[9];

    char* ws = (char*)d_ws;
    float* Wt      = (float*)(ws + OFF_WT);
    float* Wht     = (float*)(ws + OFF_WHT);
    float* x       = (float*)(ws + OFF_X);
    float* scores  = (float*)(ws + OFF_SC);
    float* boxes   = (float*)(ws + OFF_BX);
    float* sboxes  = (float*)(ws + OFF_SB);
    unsigned long long* mask = (unsigned long long*)(ws + OFF_MK);
    unsigned int* hist = (unsigned int*)(ws + OFF_HIST);
    unsigned long long* cand = (unsigned long long*)(ws + OFF_CAND);

    const int NTRANS = NT_WT + NT_WHT;
    k_wtrans<<<(NTRANS + 255) / 256, 256, 0, stream>>>(W_conv, Wt, W_cls, W_bbox, Wht);
    k_conv<<<dim3(64, 4, 2), 256, 0, stream>>>(base_feat, Wt, b_conv, x);
    // Wt region dead now; zero hist (aliases Wt) AFTER k_conv, before k_heads.
    hipMemsetAsync(hist, 0, BATCH * 65536 * sizeof(unsigned int), stream);
    k_heads<<<dim3(64, 2), 256, 0, stream>>>(x, Wht, b_cls, b_bbox, im_info, scores, boxes, hist);
    k_cutcompact<<<BATCH, 1024, 0, stream>>>(scores, hist, cand);
    k_sort2<<<BATCH, 1024, 0, stream>>>(cand, boxes, sboxes);
    k_mask<<<dim3(32, 32, 2), 256, 0, stream>>>(sboxes, mask);
    k_nms<<<BATCH, 64, 0, stream>>>(mask, sboxes, (float*)d_out);
}